// Round 6
// baseline (255.126 us; speedup 1.0000x reference)
//
#include <hip/hip_runtime.h>
#include <hip/hip_bf16.h>

// ChebConv K=3 GCN — Round 6: LDS-staged bucket sort (burst writes) + ushort2 props.
// R5 post-mortem: k_binfill 78us, WRITE 55MB for 12.8MB of payload (4.3x):
// 64 scattered 4B writes/wave into 782 cross-XCD-shared bucket regions.
// Fix: per-block LDS counting sort by bucket, then write each run as a
// contiguous 32-lane burst (boundary lines only are shared -> ~1.5-2x amp).
// Props: 8 lanes/node, ushort2 bf16 row loads -> half the load instructions.

#define NN   100000
#define NE   3200000
#define F    16
#define CB   128                  // dst nodes per bucket
#define NBUK 782                  // ceil(NN/CB)
#define ECHK 8192                 // edges per sort block (pk = 32KB LDS)
#define NBLK 391                  // ceil(NE/ECHK)
#define LCAP 5120                 // bucket cap: mean 4096, sigma~64

__device__ __forceinline__ float bf2f(unsigned short u) {
    return __uint_as_float((unsigned)u << 16);
}
__device__ __forceinline__ unsigned short f2bf(float f) {
    __hip_bfloat16 b = __float2bfloat16(f);
    return *reinterpret_cast<unsigned short*>(&b);
}

// A1: per-(block,bucket) histogram H[blk*NBUK + b]
__global__ void k_hist(const int* __restrict__ dst, int* __restrict__ H) {
    __shared__ int h[NBUK];
    for (int j = threadIdx.x; j < NBUK; j += 256) h[j] = 0;
    __syncthreads();
    int s0 = blockIdx.x * ECHK;
    int lim = min(s0 + ECHK, NE);
    for (int e = s0 + (int)threadIdx.x; e < lim; e += 256)
        atomicAdd(&h[dst[e] >> 7], 1);
    __syncthreads();
    for (int j = threadIdx.x; j < NBUK; j += 256)
        H[blockIdx.x * NBUK + j] = h[j];
}

// A2: column scan: H[:,b] -> exclusive prefix over blocks; T[b] = total.
__global__ void k_colscan(int* __restrict__ H, int* __restrict__ T) {
    __shared__ int tmp[512];
    int b = blockIdx.x, t = threadIdx.x;
    int v = (t < NBLK) ? H[t * NBUK + b] : 0;
    tmp[t] = v;
    __syncthreads();
    for (int o = 1; o < 512; o <<= 1) {
        int add = (t >= o) ? tmp[t - o] : 0;
        __syncthreads();
        tmp[t] += add;
        __syncthreads();
    }
    if (t < NBLK) H[t * NBUK + b] = tmp[t] - v;   // exclusive over blocks
    if (t == 0) T[b] = tmp[511];
}

// A3: exclusive scan of bucket totals -> base[NBUK+1]
__global__ void k_basescan(const int* __restrict__ T, int* __restrict__ base) {
    __shared__ int tmp[1024];
    int t = threadIdx.x;
    int v = (t < NBUK) ? T[t] : 0;
    tmp[t] = v;
    __syncthreads();
    for (int o = 1; o < 1024; o <<= 1) {
        int add = (t >= o) ? tmp[t - o] : 0;
        __syncthreads();
        tmp[t] += add;
        __syncthreads();
    }
    if (t < NBUK) base[t] = tmp[t] - v;
    if (t == 0) base[NBUK] = tmp[1023];
}

// A4: per-block LDS counting sort by bucket, then burst-write runs to the
// bucket-major packed[] at base[b] + H[blk][b].
__global__ __launch_bounds__(256) void k_lsort(const int* __restrict__ src,
        const int* __restrict__ dst, const int* __restrict__ H,
        const int* __restrict__ base, int* __restrict__ packed) {
    __shared__ int pk[ECHK];        // 32KB
    __shared__ int hx[1025];        // exclusive run starts within chunk
    __shared__ int cur[1024];       // bump counters, then reused as global offs
    __shared__ int csum[256];
    int t = threadIdx.x, blk = blockIdx.x;
    for (int j = t; j < 1024; j += 256) hx[j] = 0;
    __syncthreads();
    int s0 = blk * ECHK;
    int lim = min(s0 + ECHK, NE);
    for (int e = s0 + t; e < lim; e += 256)
        atomicAdd(&hx[dst[e] >> 7], 1);
    __syncthreads();
    // exclusive scan of hx[0..1023]: 4 buckets per thread + H-S over chunk sums
    int b0 = t * 4;
    int c0 = hx[b0], c1 = hx[b0 + 1], c2 = hx[b0 + 2], c3 = hx[b0 + 3];
    csum[t] = c0 + c1 + c2 + c3;
    __syncthreads();
    for (int o = 1; o < 256; o <<= 1) {
        int add = (t >= o) ? csum[t - o] : 0;
        __syncthreads();
        csum[t] += add;
        __syncthreads();
    }
    int ce = csum[t] - (c0 + c1 + c2 + c3);
    hx[b0] = ce;  hx[b0 + 1] = ce + c0;  hx[b0 + 2] = ce + c0 + c1;  hx[b0 + 3] = ce + c0 + c1 + c2;
    cur[b0] = ce; cur[b0 + 1] = ce + c0; cur[b0 + 2] = ce + c0 + c1; cur[b0 + 3] = ce + c0 + c1 + c2;
    if (t == 255) hx[1024] = csum[255];
    __syncthreads();
    // scatter into pk (re-read src/dst — L2-warm)
    for (int e = s0 + t; e < lim; e += 256) {
        int d = dst[e];
        int pos = atomicAdd(&cur[d >> 7], 1);
        pk[pos] = (src[e] << 7) | (d & 127);
    }
    __syncthreads();
    // global run offsets (reuse cur)
    for (int j = t; j < NBUK; j += 256)
        cur[j] = base[j] + H[blk * NBUK + j];
    __syncthreads();
    // burst-write runs: 8 groups of 32 lanes
    int g = t >> 5, lane = t & 31;
    for (int b = g; b < NBUK; b += 8) {
        int st = hx[b], len = hx[b + 1] - st;
        int gp = cur[b];
        for (int i = lane; i < len; i += 32)
            packed[gp + i] = pk[st + i];
    }
}

// Per-bucket exact counting sort (in-place on packed, LDS-staged) + CSR row
// pointer node_off + norm + Y0 = bf16(X0*norm).
__global__ __launch_bounds__(256) void k_sort(int* __restrict__ packed,
        const int* __restrict__ base, const float* __restrict__ X0,
        int* __restrict__ node_off, float* __restrict__ norm,
        unsigned short* __restrict__ Y0) {
    __shared__ int pk[LCAP];
    __shared__ int cnt[CB], loc[CB], cur[CB];
    __shared__ float nvs[CB];
    int b = blockIdx.x, t = threadIdx.x;
    int beg = base[b], end = base[b + 1];
    int len = end - beg;
    if (len > LCAP) len = LCAP;   // unreachable (16 sigma)
    if (t < CB) cnt[t] = 0;
    __syncthreads();
    for (int i = t; i < len; i += 256) {
        int p = packed[beg + i];
        pk[i] = p;
        atomicAdd(&cnt[p & 127], 1);
    }
    __syncthreads();
    if (t < CB) loc[t] = cnt[t];
    __syncthreads();
    for (int o = 1; o < CB; o <<= 1) {
        int add = 0;
        if (t < CB && t >= o) add = loc[t - o];
        __syncthreads();
        if (t < CB) loc[t] += add;
        __syncthreads();
    }
    if (t < CB) {
        int excl = loc[t] - cnt[t];
        loc[t] = excl;
        cur[t] = 0;
        int n = b * CB + t;
        if (n <= NN) node_off[n] = beg + excl;
        if (n < NN) {
            int c = cnt[t];
            float nv = rsqrtf((float)(c < 1 ? 1 : c));
            norm[n] = nv;
            nvs[t] = nv;
        }
    }
    __syncthreads();
    for (int j = t; j < CB * F; j += 256) {
        int dl = j >> 4;
        int n = b * CB + dl;
        if (n < NN) {
            size_t gidx = (size_t)n * F + (j & 15);
            Y0[gidx] = f2bf(X0[gidx] * nvs[dl]);
        }
    }
    for (int i = t; i < len; i += 256) {
        int p = pk[i];
        int dl = p & 127;
        int pos = beg + loc[dl] + atomicAdd(&cur[dl], 1);
        packed[pos] = p >> 7;   // now e_src, exact dst order
    }
}

// Prop 1: 8 lanes/node, lane h owns feats {2h,2h+1}; batches of 8 edges
// fully unrolled => 8 independent ushort2 row loads in flight.
__global__ __launch_bounds__(256) void k_prop1(const int* __restrict__ off,
        const int* __restrict__ es, const unsigned short* __restrict__ Y0,
        const float* __restrict__ X0, const float* __restrict__ norm,
        const float* __restrict__ lm, unsigned short* __restrict__ Y1) {
    int tid = blockIdx.x * 256 + threadIdx.x;   // NN*8 exactly
    int n = tid >> 3, h = tid & 7;
    int beg = off[n], end = off[n + 1];
    const ushort2* Yv = (const ushort2*)Y0;
    float a0 = 0.f, a1 = 0.f;
    for (int e0 = beg; e0 < end; e0 += 8) {
        int cnt = end - e0;
        int idx = (h < cnt) ? es[e0 + h] : -1;
#pragma unroll
        for (int j = 0; j < 8; ++j) {
            int s = __shfl(idx, j, 8);
            int sa = s < 0 ? 0 : s;
            ushort2 u = Yv[(size_t)sa * 8 + h];
            bool ok = s >= 0;
            a0 += ok ? bf2f(u.x) : 0.f;
            a1 += ok ? bf2f(u.y) : 0.f;
        }
    }
    float r = 2.0f / lm[0];
    float nv = norm[n];
    float2 x0 = ((const float2*)X0)[tid];
    float x1a = -r * (nv * a0) + (r - 1.0f) * x0.x;
    float x1b = -r * (nv * a1) + (r - 1.0f) * x0.y;
    ((ushort2*)Y1)[tid] = make_ushort2(f2bf(nv * x1a), f2bf(nv * x1b));
}

// Prop 2 + epilogue: x2, [x0|x1|x2]@W^T, relu; 8-lane shfl_xor reduction.
__global__ __launch_bounds__(256) void k_prop2(const int* __restrict__ off,
        const int* __restrict__ es, const unsigned short* __restrict__ Y1,
        const float* __restrict__ X0, const float* __restrict__ norm,
        const float* __restrict__ lm, const float* __restrict__ W,
        float* __restrict__ out) {
    __shared__ float Ws[96];
    if (threadIdx.x < 96) Ws[threadIdx.x] = W[threadIdx.x];
    __syncthreads();
    int tid = blockIdx.x * 256 + threadIdx.x;
    int n = tid >> 3, h = tid & 7;
    int beg = off[n], end = off[n + 1];
    const ushort2* Yv = (const ushort2*)Y1;
    float a0 = 0.f, a1 = 0.f;
    for (int e0 = beg; e0 < end; e0 += 8) {
        int cnt = end - e0;
        int idx = (h < cnt) ? es[e0 + h] : -1;
#pragma unroll
        for (int j = 0; j < 8; ++j) {
            int s = __shfl(idx, j, 8);
            int sa = s < 0 ? 0 : s;
            ushort2 u = Yv[(size_t)sa * 8 + h];
            bool ok = s >= 0;
            a0 += ok ? bf2f(u.x) : 0.f;
            a1 += ok ? bf2f(u.y) : 0.f;
        }
    }
    float r = 2.0f / lm[0];
    float nv = norm[n];
    float2 x0 = ((const float2*)X0)[tid];
    ushort2 uy = ((const ushort2*)Y1)[tid];
    float x1a = bf2f(uy.x) / nv, x1b = bf2f(uy.y) / nv;
    float c1 = -2.0f * r, c2 = 2.0f * (r - 1.0f);
    float x2a = c1 * (nv * a0) + c2 * x1a - x0.x;
    float x2b = c1 * (nv * a1) + c2 * x1b - x0.y;
    int f0 = 2 * h, f1 = 2 * h + 1;
    float t0 = Ws[f0] * x0.x + Ws[f1] * x0.y + Ws[16 + f0] * x1a + Ws[16 + f1] * x1b
             + Ws[32 + f0] * x2a + Ws[32 + f1] * x2b;
    float t1 = Ws[48 + f0] * x0.x + Ws[48 + f1] * x0.y + Ws[64 + f0] * x1a + Ws[64 + f1] * x1b
             + Ws[80 + f0] * x2a + Ws[80 + f1] * x2b;
    for (int o = 4; o >= 1; o >>= 1) {
        t0 += __shfl_xor(t0, o, 8);
        t1 += __shfl_xor(t1, o, 8);
    }
    if (h == 0) {
        out[(size_t)n * 2 + 0] = fmaxf(t0, 0.f);
        out[(size_t)n * 2 + 1] = fmaxf(t1, 0.f);
    }
}

extern "C" void kernel_launch(void* const* d_in, const int* in_sizes, int n_in,
                              void* d_out, int out_size, void* d_ws, size_t ws_size,
                              hipStream_t stream) {
    const float* X0  = (const float*)d_in[0];
    const float* W   = (const float*)d_in[1];
    const int*   src = (const int*)d_in[2];
    const int*   dst = (const int*)d_in[3];
    const float* lm  = (const float*)d_in[4];
    float* out = (float*)d_out;

    // Workspace (~21.4 MB):
    // H[NBLK*NBUK] | T[NBUK] | base[NBUK+1] | packed[NE] | node_off[NN+1]
    // | norm[NN] | Y0[NN*F bf16] | Y1[NN*F bf16]
    int*   H        = (int*)d_ws;
    int*   T        = H + (size_t)NBLK * NBUK;
    int*   base     = T + NBUK;
    int*   packed   = base + (NBUK + 1);
    int*   node_off = packed + NE;
    float* norm     = (float*)(node_off + (NN + 1));
    unsigned short* Y0 = (unsigned short*)(norm + NN);
    unsigned short* Y1 = Y0 + (size_t)NN * F;

    const int gridP = NN * 8 / 256;   // 3125

    k_hist    <<<NBLK, 256, 0, stream>>>(dst, H);
    k_colscan <<<NBUK, 512, 0, stream>>>(H, T);
    k_basescan<<<1, 1024, 0, stream>>>(T, base);
    k_lsort   <<<NBLK, 256, 0, stream>>>(src, dst, H, base, packed);
    k_sort    <<<NBUK, 256, 0, stream>>>(packed, base, X0, node_off, norm, Y0);
    k_prop1   <<<gridP, 256, 0, stream>>>(node_off, packed, Y0, X0, norm, lm, Y1);
    k_prop2   <<<gridP, 256, 0, stream>>>(node_off, packed, Y1, X0, norm, lm, W, out);
}

// Round 7
// 191.609 us; speedup vs baseline: 1.3315x; 1.3315x over previous
//
#include <hip/hip_runtime.h>
#include <hip/hip_bf16.h>

// ChebConv K=3 GCN — Round 7: wider lsort blocks + 4-lane uint2 props + zero-row sentinel.
// R6 post-mortem: k_lsort 57us was parallelism-starved (391 blocks x 4 waves
// = 6 waves/CU; occupancy 12%), not BW-bound (34MB traffic). Fix: 512-thread
// blocks (12 waves/CU, half the serial chain), same chunk size so write amp
// stays at the measured ~21MB. Props: 4 lanes/node loading uint2 (8B) halves
// gather instrs to 12.8M/pass; invalid lanes redirect to a zero row at Y[NN]
// (no cndmask in the inner loop).

#define NN   100000
#define NE   3200000
#define F    16
#define CB   128                  // dst nodes per bucket
#define NBUK 782                  // ceil(NN/CB)
#define ECHK 8192                 // edges per sort chunk
#define NBLK 391                  // ceil(NE/ECHK)
#define LCAP 5120                 // bucket cap: mean 4096, sigma~64

__device__ __forceinline__ float bflo(unsigned int u) {
    return __uint_as_float(u << 16);
}
__device__ __forceinline__ float bfhi(unsigned int u) {
    return __uint_as_float(u & 0xffff0000u);
}
__device__ __forceinline__ unsigned int f2bf(float f) {
    __hip_bfloat16 b = __float2bfloat16(f);
    return (unsigned int)*reinterpret_cast<unsigned short*>(&b);
}

// A1: per-(chunk,bucket) histogram H[blk*NBUK + b]
__global__ void k_hist(const int* __restrict__ dst, int* __restrict__ H) {
    __shared__ int h[NBUK];
    for (int j = threadIdx.x; j < NBUK; j += 256) h[j] = 0;
    __syncthreads();
    int s0 = blockIdx.x * ECHK;
    int lim = min(s0 + ECHK, NE);
    for (int e = s0 + (int)threadIdx.x; e < lim; e += 256)
        atomicAdd(&h[dst[e] >> 7], 1);
    __syncthreads();
    for (int j = threadIdx.x; j < NBUK; j += 256)
        H[blockIdx.x * NBUK + j] = h[j];
}

// A2: column scan: H[:,b] -> exclusive prefix over chunks; T[b] = total.
__global__ void k_colscan(int* __restrict__ H, int* __restrict__ T) {
    __shared__ int tmp[512];
    int b = blockIdx.x, t = threadIdx.x;
    int v = (t < NBLK) ? H[t * NBUK + b] : 0;
    tmp[t] = v;
    __syncthreads();
    for (int o = 1; o < 512; o <<= 1) {
        int add = (t >= o) ? tmp[t - o] : 0;
        __syncthreads();
        tmp[t] += add;
        __syncthreads();
    }
    if (t < NBLK) H[t * NBUK + b] = tmp[t] - v;   // exclusive over chunks
    if (t == 0) T[b] = tmp[511];
}

// A3: exclusive scan of bucket totals -> base[NBUK+1]
__global__ void k_basescan(const int* __restrict__ T, int* __restrict__ base) {
    __shared__ int tmp[1024];
    int t = threadIdx.x;
    int v = (t < NBUK) ? T[t] : 0;
    tmp[t] = v;
    __syncthreads();
    for (int o = 1; o < 1024; o <<= 1) {
        int add = (t >= o) ? tmp[t - o] : 0;
        __syncthreads();
        tmp[t] += add;
        __syncthreads();
    }
    if (t < NBUK) base[t] = tmp[t] - v;
    if (t == 0) base[NBUK] = tmp[1023];
}

// A4: per-chunk LDS counting sort by bucket, burst-write runs. 512 threads.
__global__ __launch_bounds__(512) void k_lsort(const int* __restrict__ src,
        const int* __restrict__ dst, const int* __restrict__ H,
        const int* __restrict__ base, int* __restrict__ packed) {
    __shared__ int pk[ECHK];        // 32KB
    __shared__ int hx[1025];        // run starts within chunk
    __shared__ int cur[1024];       // bump counters -> reused as global offs
    __shared__ int csum[512];
    int t = threadIdx.x, blk = blockIdx.x;
    for (int j = t; j < 1024; j += 512) hx[j] = 0;
    __syncthreads();
    int s0 = blk * ECHK;
    int lim = min(s0 + ECHK, NE);
    for (int e = s0 + t; e < lim; e += 512)
        atomicAdd(&hx[dst[e] >> 7], 1);
    __syncthreads();
    // exclusive scan of hx[0..1023]: 2 buckets/thread + H-S over thread sums
    int b0 = t * 2;
    int c0 = hx[b0], c1 = hx[b0 + 1];
    csum[t] = c0 + c1;
    __syncthreads();
    for (int o = 1; o < 512; o <<= 1) {
        int add = (t >= o) ? csum[t - o] : 0;
        __syncthreads();
        csum[t] += add;
        __syncthreads();
    }
    int ce = csum[t] - (c0 + c1);
    hx[b0] = ce;  hx[b0 + 1] = ce + c0;
    cur[b0] = ce; cur[b0 + 1] = ce + c0;
    if (t == 511) hx[1024] = csum[511];
    __syncthreads();
    // scatter into pk (src/dst L2-warm from hist pass)
    for (int e = s0 + t; e < lim; e += 512) {
        int d = dst[e];
        int pos = atomicAdd(&cur[d >> 7], 1);
        pk[pos] = (src[e] << 7) | (d & 127);
    }
    __syncthreads();
    // global run offsets (reuse cur)
    for (int j = t; j < NBUK; j += 512)
        cur[j] = base[j] + H[blk * NBUK + j];
    __syncthreads();
    // burst-write runs: 64 groups of 8 lanes (mean run len 10.5)
    int g = t >> 3, lane = t & 7;
    for (int b = g; b < NBUK; b += 64) {
        int st = hx[b], len = hx[b + 1] - st;
        int gp = cur[b];
        for (int i = lane; i < len; i += 8)
            packed[gp + i] = pk[st + i];
    }
}

// Per-bucket exact counting sort (in-place, LDS-staged) + CSR node_off + norm
// + Y0 = bf16(X0*norm) (+ zero row at Y0[NN]).
__global__ __launch_bounds__(256) void k_sort(int* __restrict__ packed,
        const int* __restrict__ base, const float* __restrict__ X0,
        int* __restrict__ node_off, float* __restrict__ norm,
        unsigned short* __restrict__ Y0) {
    __shared__ int pk[LCAP];
    __shared__ int cnt[CB], loc[CB], cur[CB];
    __shared__ float nvs[CB];
    int b = blockIdx.x, t = threadIdx.x;
    int beg = base[b], end = base[b + 1];
    int len = end - beg;
    if (len > LCAP) len = LCAP;   // unreachable (16 sigma)
    if (t < CB) cnt[t] = 0;
    if (b == 0 && t < F) Y0[(size_t)NN * F + t] = 0;   // sentinel zero row
    __syncthreads();
    for (int i = t; i < len; i += 256) {
        int p = packed[beg + i];
        pk[i] = p;
        atomicAdd(&cnt[p & 127], 1);
    }
    __syncthreads();
    if (t < CB) loc[t] = cnt[t];
    __syncthreads();
    for (int o = 1; o < CB; o <<= 1) {
        int add = 0;
        if (t < CB && t >= o) add = loc[t - o];
        __syncthreads();
        if (t < CB) loc[t] += add;
        __syncthreads();
    }
    if (t < CB) {
        int excl = loc[t] - cnt[t];
        loc[t] = excl;
        cur[t] = 0;
        int n = b * CB + t;
        if (n <= NN) node_off[n] = beg + excl;
        if (n < NN) {
            int c = cnt[t];
            float nv = rsqrtf((float)(c < 1 ? 1 : c));
            norm[n] = nv;
            nvs[t] = nv;
        }
    }
    __syncthreads();
    for (int j = t; j < CB * F; j += 256) {
        int dl = j >> 4;
        int n = b * CB + dl;
        if (n < NN) {
            size_t gidx = (size_t)n * F + (j & 15);
            Y0[gidx] = (unsigned short)f2bf(X0[gidx] * nvs[dl]);
        }
    }
    for (int i = t; i < len; i += 256) {
        int p = pk[i];
        int dl = p & 127;
        int pos = beg + loc[dl] + atomicAdd(&cur[dl], 1);
        packed[pos] = p >> 7;   // now e_src, exact dst order
    }
}

// Prop 1: 4 lanes/node, lane h owns feats {4h..4h+3} (uint2 = 8B). Two 4-edge
// batches unrolled => 8 independent loads in flight. Invalid lanes gather the
// zero row at index NN (no masking ops).
__global__ __launch_bounds__(256) void k_prop1(const int* __restrict__ off,
        const int* __restrict__ es, const unsigned short* __restrict__ Y0,
        const float* __restrict__ X0, const float* __restrict__ norm,
        const float* __restrict__ lm, unsigned short* __restrict__ Y1) {
    int tid = blockIdx.x * 256 + threadIdx.x;   // NN*4 (+ tail guard)
    if (tid < 4) ((uint2*)Y1)[(size_t)NN * 4 + tid] = make_uint2(0u, 0u);
    int n = tid >> 2, h = tid & 3;
    if (n >= NN) return;
    int beg = off[n], end = off[n + 1];
    const uint2* Yv = (const uint2*)Y0;
    float a0 = 0.f, a1 = 0.f, a2 = 0.f, a3 = 0.f;
    for (int e0 = beg; e0 < end; e0 += 8) {
        int c = end - e0;
        int iA = (h < c)     ? es[e0 + h]     : NN;
        int iB = (4 + h < c) ? es[e0 + 4 + h] : NN;
#pragma unroll
        for (int j = 0; j < 4; ++j) {
            int s = __shfl(iA, j, 4);
            uint2 u = Yv[(size_t)s * 4 + h];
            a0 += bflo(u.x); a1 += bfhi(u.x);
            a2 += bflo(u.y); a3 += bfhi(u.y);
        }
#pragma unroll
        for (int j = 0; j < 4; ++j) {
            int s = __shfl(iB, j, 4);
            uint2 u = Yv[(size_t)s * 4 + h];
            a0 += bflo(u.x); a1 += bfhi(u.x);
            a2 += bflo(u.y); a3 += bfhi(u.y);
        }
    }
    float r  = 2.0f / lm[0];
    float nv = norm[n];
    float k1 = -r * nv, k2 = r - 1.0f;
    float4 x0 = ((const float4*)X0)[tid];
    float x1a = k1 * a0 + k2 * x0.x;
    float x1b = k1 * a1 + k2 * x0.y;
    float x1c = k1 * a2 + k2 * x0.z;
    float x1d = k1 * a3 + k2 * x0.w;
    uint2 o;
    o.x = f2bf(nv * x1a) | (f2bf(nv * x1b) << 16);
    o.y = f2bf(nv * x1c) | (f2bf(nv * x1d) << 16);
    ((uint2*)Y1)[tid] = o;
}

// Prop 2 + epilogue: x2, [x0|x1|x2]@W^T, relu; 4-lane shfl_xor reduction.
__global__ __launch_bounds__(256) void k_prop2(const int* __restrict__ off,
        const int* __restrict__ es, const unsigned short* __restrict__ Y1,
        const float* __restrict__ X0, const float* __restrict__ norm,
        const float* __restrict__ lm, const float* __restrict__ W,
        float* __restrict__ out) {
    __shared__ float Ws[96];
    if (threadIdx.x < 96) Ws[threadIdx.x] = W[threadIdx.x];
    __syncthreads();
    int tid = blockIdx.x * 256 + threadIdx.x;
    int n = tid >> 2, h = tid & 3;
    if (n >= NN) return;
    int beg = off[n], end = off[n + 1];
    const uint2* Yv = (const uint2*)Y1;
    float a0 = 0.f, a1 = 0.f, a2 = 0.f, a3 = 0.f;
    for (int e0 = beg; e0 < end; e0 += 8) {
        int c = end - e0;
        int iA = (h < c)     ? es[e0 + h]     : NN;
        int iB = (4 + h < c) ? es[e0 + 4 + h] : NN;
#pragma unroll
        for (int j = 0; j < 4; ++j) {
            int s = __shfl(iA, j, 4);
            uint2 u = Yv[(size_t)s * 4 + h];
            a0 += bflo(u.x); a1 += bfhi(u.x);
            a2 += bflo(u.y); a3 += bfhi(u.y);
        }
#pragma unroll
        for (int j = 0; j < 4; ++j) {
            int s = __shfl(iB, j, 4);
            uint2 u = Yv[(size_t)s * 4 + h];
            a0 += bflo(u.x); a1 += bfhi(u.x);
            a2 += bflo(u.y); a3 += bfhi(u.y);
        }
    }
    float r  = 2.0f / lm[0];
    float nv = norm[n];
    float rn = 1.0f / nv;
    float4 x0 = ((const float4*)X0)[tid];
    uint2 uy = ((const uint2*)Y1)[tid];
    float x1a = bflo(uy.x) * rn, x1b = bfhi(uy.x) * rn;
    float x1c = bflo(uy.y) * rn, x1d = bfhi(uy.y) * rn;
    float c1 = -2.0f * r * nv, c2 = 2.0f * (r - 1.0f);
    float x2a = c1 * a0 + c2 * x1a - x0.x;
    float x2b = c1 * a1 + c2 * x1b - x0.y;
    float x2c = c1 * a2 + c2 * x1c - x0.z;
    float x2d = c1 * a3 + c2 * x1d - x0.w;
    int f0 = 4 * h;
    float t0 = Ws[f0] * x0.x + Ws[f0 + 1] * x0.y + Ws[f0 + 2] * x0.z + Ws[f0 + 3] * x0.w
             + Ws[16 + f0] * x1a + Ws[17 + f0] * x1b + Ws[18 + f0] * x1c + Ws[19 + f0] * x1d
             + Ws[32 + f0] * x2a + Ws[33 + f0] * x2b + Ws[34 + f0] * x2c + Ws[35 + f0] * x2d;
    float t1 = Ws[48 + f0] * x0.x + Ws[49 + f0] * x0.y + Ws[50 + f0] * x0.z + Ws[51 + f0] * x0.w
             + Ws[64 + f0] * x1a + Ws[65 + f0] * x1b + Ws[66 + f0] * x1c + Ws[67 + f0] * x1d
             + Ws[80 + f0] * x2a + Ws[81 + f0] * x2b + Ws[82 + f0] * x2c + Ws[83 + f0] * x2d;
    t0 += __shfl_xor(t0, 2, 4); t0 += __shfl_xor(t0, 1, 4);
    t1 += __shfl_xor(t1, 2, 4); t1 += __shfl_xor(t1, 1, 4);
    if (h == 0) {
        out[(size_t)n * 2 + 0] = fmaxf(t0, 0.f);
        out[(size_t)n * 2 + 1] = fmaxf(t1, 0.f);
    }
}

extern "C" void kernel_launch(void* const* d_in, const int* in_sizes, int n_in,
                              void* d_out, int out_size, void* d_ws, size_t ws_size,
                              hipStream_t stream) {
    const float* X0  = (const float*)d_in[0];
    const float* W   = (const float*)d_in[1];
    const int*   src = (const int*)d_in[2];
    const int*   dst = (const int*)d_in[3];
    const float* lm  = (const float*)d_in[4];
    float* out = (float*)d_out;

    // Workspace (~21.3 MB):
    // H[NBLK*NBUK] | T[NBUK] | base[NBUK+1] | packed[NE] | node_off[NN+1]
    // | norm[NN] | Y0[(NN+1)*F bf16] | Y1[(NN+1)*F bf16]
    int*   H        = (int*)d_ws;
    int*   T        = H + (size_t)NBLK * NBUK;
    int*   base     = T + NBUK;
    int*   packed   = base + (NBUK + 1);
    int*   node_off = packed + NE;
    float* norm     = (float*)(node_off + (NN + 1));
    unsigned short* Y0 = (unsigned short*)(norm + NN);
    unsigned short* Y1 = Y0 + (size_t)(NN + 1) * F;

    const int gridP = (NN * 4 + 255) / 256;   // 1563

    k_hist    <<<NBLK, 256, 0, stream>>>(dst, H);
    k_colscan <<<NBUK, 512, 0, stream>>>(H, T);
    k_basescan<<<1, 1024, 0, stream>>>(T, base);
    k_lsort   <<<NBLK, 512, 0, stream>>>(src, dst, H, base, packed);
    k_sort    <<<NBUK, 256, 0, stream>>>(packed, base, X0, node_off, norm, Y0);
    k_prop1   <<<gridP, 256, 0, stream>>>(node_off, packed, Y0, X0, norm, lm, Y1);
    k_prop2   <<<gridP, 256, 0, stream>>>(node_off, packed, Y1, X0, norm, lm, W, out);
}